// Round 1
// baseline (282.120 us; speedup 1.0000x reference)
//
#include <hip/hip_runtime.h>

#define L2E 1.44269504088896340736f
#define LN2 0.69314718055994530942f

typedef float f32x4 __attribute__((ext_vector_type(4)));
typedef __bf16 bf16x8 __attribute__((ext_vector_type(8)));

// problem sizes
static constexpr int NB = 64, NS = 512, NH = 768, NT = 500, NM = 8;

// workspace layout (bytes)
static constexpr size_t WT_ALL_OFF   = 0;        // 80*768 bf16   = 122880
static constexpr size_t WT_TYPE_OFF  = 122880;   // 512*768 bf16  = 786432
static constexpr size_t EM_T_OFF     = 909312;   // 512*3*64 f32  = 393216  (em_t[s][j][b])
static constexpr size_t SCORES_OFF   = 1302528;  // 64*512 f32    = 131072  (scores[b][s])
static constexpr size_t LABELS_T_OFF = 1433600;  // 512*64 i32    = 131072  (labels_t[s][b])
static constexpr size_t LEN_OFF      = 1564672;  // 64 i32
static constexpr size_t POOLED_OFF   = 1564928;  // 512*768 bf16  = 786432
static constexpr size_t LOGITS_OFF   = 2351360;  // 512*512 f32   = 1048576
static constexpr size_t SCAL_OFF     = 3399936;  // 4 f32: [pos_loss, focal_sum, v_sum, -]

__device__ __forceinline__ unsigned short f2bf(float f) {
  unsigned u = __builtin_bit_cast(unsigned, f);
  u += 0x7FFFu + ((u >> 16) & 1u);
  return (unsigned short)(u >> 16);
}
__device__ __forceinline__ float sel3(float a, float b, float c, int i) {
  return i == 0 ? a : (i == 1 ? b : c);
}
__device__ __forceinline__ float lse3(float x, float y, float z) {
  float m = fmaxf(fmaxf(x, y), z);
  float p = exp2f((x - m) * L2E) + exp2f((y - m) * L2E) + exp2f((z - m) * L2E);
  return m + log2f(p) * LN2;
}
__device__ __forceinline__ int swz(int row, int slot) {       // byte addr of 16B slot, XOR-swizzled
  return row * 128 + ((slot ^ (row & 7)) << 4);
}

// ---------------- K0: weight prep (bf16 transposed), lengths, zero accumulators ------------
__global__ __launch_bounds__(256) void k0_prep(
    const float* __restrict__ W1, const float* __restrict__ Wpos,
    const float* __restrict__ Wtype, const int* __restrict__ amask,
    unsigned short* __restrict__ wt_all, unsigned short* __restrict__ wt_type,
    int* __restrict__ lengths, float* __restrict__ scal) {
  __shared__ int part[256];
  int gid = blockIdx.x * 256 + threadIdx.x;
  if (gid < 80 * 768) {                         // wt_all[n][k]: n<64 att_W1 col, 64..66 W_pos col, else 0
    int n = gid / 768, k = gid % 768;
    float v = (n < 64) ? W1[k * 64 + n] : ((n < 67) ? Wpos[k * 3 + (n - 64)] : 0.f);
    wt_all[gid] = f2bf(v);
  } else if (gid < 80 * 768 + 512 * 768) {      // wt_type[n][k], n<500 from W_type col, else 0
    int g = gid - 80 * 768;
    int n = g / 768, k = g % 768;
    float v = (n < 500) ? Wtype[k * 500 + n] : 0.f;
    wt_type[g] = f2bf(v);
  } else {                                       // last block: lengths + scalar zeroing
    int tt = gid - (80 * 768 + 512 * 768);      // 0..255
    int bb = tt >> 2, qq = tt & 3;
    const int4* mp = (const int4*)(amask + bb * 512 + qq * 128);
    int s = 0;
    #pragma unroll 8
    for (int i = 0; i < 32; ++i) { int4 v = mp[i]; s += v.x + v.y + v.z + v.w; }
    part[tt] = s;
    __syncthreads();
    if (qq == 0) lengths[bb] = part[tt] + part[tt + 1] + part[tt + 2] + part[tt + 3];
    if (tt == 0) { scal[1] = 0.f; scal[2] = 0.f; }
  }
}

// ---------------- K1: fused [32768x768]@[768x80] bf16 MFMA + epilogue ------------------------
// cols 0..63 = att pre-act -> tanh*W2 reduce -> scores; cols 64..66 = emissions (weighted)
__global__ __launch_bounds__(256) void k1_gemm(
    const float* __restrict__ hidden, const int* __restrict__ plab,
    const float* __restrict__ bpos, const float* __restrict__ b1,
    const float* __restrict__ W2, const float* __restrict__ b2,
    const float* __restrict__ biw, const unsigned short* __restrict__ wt_all,
    float* __restrict__ em_t, float* __restrict__ scores, int* __restrict__ labels_t) {
  __shared__ char lds[8192 + 10240];
  char* As = lds;            // [64 rows][64 k] bf16, swizzled 16B slots
  char* Bs = lds + 8192;     // [80 n  ][64 k] bf16, swizzled
  const int t = threadIdx.x, w = t >> 6, l = t & 63;
  const int row0 = blockIdx.x * 64;

  f32x4 acc[5];
  #pragma unroll
  for (int nt = 0; nt < 5; ++nt) acc[nt] = (f32x4){0.f, 0.f, 0.f, 0.f};

  for (int it = 0; it < 12; ++it) {
    const int k0 = it * 64;
    // global loads (A fp32, B bf16)
    float4 av[4];
    #pragma unroll
    for (int u = 0; u < 4; ++u) {
      int f4 = t + 256 * u, r = f4 >> 4, k4 = f4 & 15;
      av[u] = *(const float4*)(hidden + (size_t)(row0 + r) * 768 + k0 + 4 * k4);
    }
    uint4 bv0 = *(const uint4*)(wt_all + (t >> 3) * 768 + k0 + 8 * (t & 7));
    uint4 bv1 = *(const uint4*)(wt_all + ((t + 256) >> 3) * 768 + k0 + 8 * (t & 7));
    uint4 bv2 = (t < 128) ? *(const uint4*)(wt_all + ((t + 512) >> 3) * 768 + k0 + 8 * (t & 7))
                          : (uint4){0, 0, 0, 0};
    __syncthreads();   // previous iteration's LDS reads done
    #pragma unroll
    for (int u = 0; u < 4; ++u) {
      int f4 = t + 256 * u, r = f4 >> 4, k4 = f4 & 15;
      unsigned lo = (unsigned)f2bf(av[u].x) | ((unsigned)f2bf(av[u].y) << 16);
      unsigned hi = (unsigned)f2bf(av[u].z) | ((unsigned)f2bf(av[u].w) << 16);
      int byte = r * 128 + (((k4 >> 1) ^ (r & 7)) << 4) + (k4 & 1) * 8;
      *(uint2*)(As + byte) = make_uint2(lo, hi);
    }
    { int n = t >> 3, kc = t & 7;         *(uint4*)(Bs + swz(n, kc)) = bv0; }
    { int n = (t + 256) >> 3, kc = t & 7; *(uint4*)(Bs + swz(n, kc)) = bv1; }
    if (t < 128) { int n = (t + 512) >> 3, kc = t & 7; *(uint4*)(Bs + swz(n, kc)) = bv2; }
    __syncthreads();
    #pragma unroll
    for (int ks = 0; ks < 2; ++ks) {
      int arow = 16 * w + (l & 15);
      int slot = 4 * ks + (l >> 4);
      bf16x8 a = *(const bf16x8*)(As + swz(arow, slot));
      #pragma unroll
      for (int nt = 0; nt < 5; ++nt) {
        int brow = 16 * nt + (l & 15);
        bf16x8 b = *(const bf16x8*)(Bs + swz(brow, slot));
        acc[nt] = __builtin_amdgcn_mfma_f32_16x16x32_bf16(a, b, acc[nt], 0, 0, 0);
      }
    }
  }

  // epilogue: D layout col = l&15 (+16*nt), row = 16*w + 4*(l>>4) + reg
  const int q = l >> 4, c16 = l & 15;
  const float bias2 = b2[0];
  #pragma unroll
  for (int r = 0; r < 4; ++r) {
    float s = 0.f;
    #pragma unroll
    for (int nt = 0; nt < 4; ++nt) {
      int c = 16 * nt + c16;
      float x = acc[nt][r] + b1[c];
      float th = 1.f - 2.f / (1.f + exp2f(x * (2.f * L2E)));
      s += th * W2[c];
    }
    #pragma unroll
    for (int off = 1; off < 16; off <<= 1) s += __shfl_xor(s, off, 64);
    if (c16 == 0) {
      int row = row0 + 16 * w + 4 * q + r;
      scores[row] = s + bias2;
    }
  }
  if (c16 < 3) {
    const float bi = biw[0];
    #pragma unroll
    for (int r = 0; r < 4; ++r) {
      int row = row0 + 16 * w + 4 * q + r;
      int bb = row >> 9, ss = row & 511;
      int lab = plab[row];
      float wgt = (lab > 0) ? 1.f + bi : 1.f;
      float ev = (acc[4][r] + bpos[c16]) * wgt;
      em_t[(ss * 3 + c16) * 64 + bb] = ev;
      if (c16 == 0) labels_t[ss * 64 + bb] = lab;
    }
  }
}

// ---------------- K2: CRF forward + gold score, one lane per sequence ------------------------
__global__ __launch_bounds__(64) void k2_crf(
    const float* __restrict__ em_t, const int* __restrict__ labels_t,
    const int* __restrict__ lengths, const float* __restrict__ strans,
    const float* __restrict__ etrans, const float* __restrict__ trans,
    float* __restrict__ scal) {
  const int b = threadIdx.x;
  float tr[9];
  #pragma unroll
  for (int i = 0; i < 9; ++i) tr[i] = trans[i];
  const float st0 = strans[0], st1 = strans[1], st2 = strans[2];
  const float et0 = etrans[0], et1 = etrans[1], et2 = etrans[2];
  const int L = lengths[b];

  float e0 = em_t[0 * 64 + b], e1 = em_t[1 * 64 + b], e2 = em_t[2 * 64 + b];
  int lab0 = labels_t[b];
  float a0 = st0 + e0, a1 = st1 + e1, a2 = st2 + e2;
  float score = sel3(st0, st1, st2, lab0) + sel3(e0, e1, e2, lab0);
  int prev = lab0, last = lab0;

  for (int s = 1; s < 512; ++s) {
    float f0 = em_t[(s * 3 + 0) * 64 + b];
    float f1 = em_t[(s * 3 + 1) * 64 + b];
    float f2 = em_t[(s * 3 + 2) * 64 + b];
    int lab = labels_t[s * 64 + b];
    bool act = s < L;
    float n0 = lse3(a0 + tr[0], a1 + tr[3], a2 + tr[6]) + f0;
    float n1 = lse3(a0 + tr[1], a1 + tr[4], a2 + tr[7]) + f1;
    float n2 = lse3(a0 + tr[2], a1 + tr[5], a2 + tr[8]) + f2;
    a0 = act ? n0 : a0; a1 = act ? n1 : a1; a2 = act ? n2 : a2;
    float trv = sel3(sel3(tr[0], tr[1], tr[2], lab),
                     sel3(tr[3], tr[4], tr[5], lab),
                     sel3(tr[6], tr[7], tr[8], lab), prev);
    score += act ? (sel3(f0, f1, f2, lab) + trv) : 0.f;
    last = (s == L - 1) ? lab : last;
    prev = lab;
  }
  score += sel3(et0, et1, et2, last);
  float logZ = lse3(a0 + et0, a1 + et1, a2 + et2);
  float nll = logZ - score;
  #pragma unroll
  for (int off = 1; off < 64; off <<= 1) nll += __shfl_xor(nll, off, 64);
  if (b == 0) scal[0] = nll / 64.f;
}

// ---------------- K3: span softmax-pooling, one wave per (b,m) span --------------------------
__global__ __launch_bounds__(64) void k3_pool(
    const float* __restrict__ hidden, const float* __restrict__ scores,
    const int* __restrict__ tpos, unsigned short* __restrict__ pooled) {
  const int span = blockIdx.x, l = threadIdx.x;
  const int b = span >> 3;
  const int st = tpos[span * 2], en = tpos[span * 2 + 1];
  int len = (st + en > 0) ? (en - st) : 0;      // invalid -> 0 -> pooled = 0
  float sv[7], aw[7];
  float wm = -1e30f;
  #pragma unroll
  for (int j = 0; j < 7; ++j) {
    sv[j] = (j < len) ? scores[b * 512 + st + j] : -1e30f;
    wm = fmaxf(wm, sv[j]);
  }
  float den = 0.f;
  #pragma unroll
  for (int j = 0; j < 7; ++j) {
    aw[j] = (j < len) ? exp2f((sv[j] - wm) * L2E) : 0.f;
    den += aw[j];
  }
  float inv = (den > 0.f) ? 1.f / den : 0.f;
  #pragma unroll
  for (int j = 0; j < 7; ++j) aw[j] *= inv;
  #pragma unroll
  for (int r = 0; r < 12; ++r) {
    int h = l + 64 * r;
    float acc = 0.f;
    #pragma unroll
    for (int j = 0; j < 7; ++j)
      if (j < len) acc += aw[j] * hidden[(size_t)(b * 512 + st + j) * 768 + h];
    pooled[span * 768 + h] = f2bf(acc);
  }
}

// ---------------- K3b: [512x768]@[768x512(500 pad)] bf16 MFMA -> logits ----------------------
__global__ __launch_bounds__(256) void k3b_gemm(
    const unsigned short* __restrict__ pooled, const unsigned short* __restrict__ wt_type,
    const float* __restrict__ btype, float* __restrict__ logits) {
  __shared__ char lds[8192 + 16384];
  char* As = lds;           // [64][64] bf16 swizzled
  char* Bs = lds + 8192;    // [128][64] bf16 swizzled
  const int t = threadIdx.x, w = t >> 6, l = t & 63;
  const int row0 = (blockIdx.x >> 2) * 64, n0 = (blockIdx.x & 3) * 128;

  f32x4 acc[8];
  #pragma unroll
  for (int nt = 0; nt < 8; ++nt) acc[nt] = (f32x4){0.f, 0.f, 0.f, 0.f};

  for (int it = 0; it < 12; ++it) {
    const int k0 = it * 64;
    uint4 av[2], bvv[4];
    #pragma unroll
    for (int u = 0; u < 2; ++u) {
      int idx = t + 256 * u, r = idx >> 3, kc = idx & 7;
      av[u] = *(const uint4*)(pooled + (size_t)(row0 + r) * 768 + k0 + 8 * kc);
    }
    #pragma unroll
    for (int u = 0; u < 4; ++u) {
      int idx = t + 256 * u, n = idx >> 3, kc = idx & 7;
      bvv[u] = *(const uint4*)(wt_type + (size_t)(n0 + n) * 768 + k0 + 8 * kc);
    }
    __syncthreads();
    #pragma unroll
    for (int u = 0; u < 2; ++u) {
      int idx = t + 256 * u, r = idx >> 3, kc = idx & 7;
      *(uint4*)(As + swz(r, kc)) = av[u];
    }
    #pragma unroll
    for (int u = 0; u < 4; ++u) {
      int idx = t + 256 * u, n = idx >> 3, kc = idx & 7;
      *(uint4*)(Bs + swz(n, kc)) = bvv[u];
    }
    __syncthreads();
    #pragma unroll
    for (int ks = 0; ks < 2; ++ks) {
      int arow = 16 * w + (l & 15);
      int slot = 4 * ks + (l >> 4);
      bf16x8 a = *(const bf16x8*)(As + swz(arow, slot));
      #pragma unroll
      for (int nt = 0; nt < 8; ++nt) {
        int brow = 16 * nt + (l & 15);
        bf16x8 b = *(const bf16x8*)(Bs + swz(brow, slot));
        acc[nt] = __builtin_amdgcn_mfma_f32_16x16x32_bf16(a, b, acc[nt], 0, 0, 0);
      }
    }
  }
  const int q = l >> 4, c16 = l & 15;
  #pragma unroll
  for (int nt = 0; nt < 8; ++nt) {
    int col = n0 + 16 * nt + c16;
    #pragma unroll
    for (int r = 0; r < 4; ++r) {
      int row = row0 + 16 * w + 4 * q + r;
      float v = (col < 500) ? acc[nt][r] + btype[col] : -1e30f;
      logits[row * 512 + col] = v;
    }
  }
}

// ---------------- K4: per-span label-smoothed focal CE, atomic accumulate --------------------
__global__ __launch_bounds__(256) void k4_focal(
    const float* __restrict__ logits, const int* __restrict__ tlab,
    const int* __restrict__ tpos, float* __restrict__ scal) {
  const int w = threadIdx.x >> 6, l = threadIdx.x & 63;
  const int row = blockIdx.x * 4 + w;
  float v[8];
  #pragma unroll
  for (int j = 0; j < 8; ++j) v[j] = logits[row * 512 + l + 64 * j];
  float m = v[0];
  #pragma unroll
  for (int j = 1; j < 8; ++j) m = fmaxf(m, v[j]);
  #pragma unroll
  for (int off = 1; off < 64; off <<= 1) m = fmaxf(m, __shfl_xor(m, off, 64));
  float p = 0.f, slog = 0.f;
  #pragma unroll
  for (int j = 0; j < 8; ++j) {
    p += exp2f((v[j] - m) * L2E);                 // padded cols are -1e30 -> 0
    slog += (l + 64 * j < 500) ? v[j] : 0.f;
  }
  #pragma unroll
  for (int off = 1; off < 64; off <<= 1) {
    p += __shfl_xor(p, off, 64);
    slog += __shfl_xor(slog, off, 64);
  }
  float logZ = m + log2f(p) * LN2;
  int lbl = tlab[row];
  float vl = logits[row * 512 + lbl];
  float lp = vl - logZ;
  float ce = -(0.9f * lp + 2e-4f * (slog - 500.f * logZ));
  float pt = 0.9f * exp2f(lp * L2E) + 2e-4f;
  float focal = ce * (1.f - pt) * (1.f - pt);
  bool valid = (tpos[row * 2] + tpos[row * 2 + 1]) > 0;
  if (l == 0 && valid) {
    atomicAdd(&scal[1], focal);
    atomicAdd(&scal[2], 1.f);
  }
}

// ---------------- K5: combine --------------------------------------------------------------
__global__ void k5_final(const float* __restrict__ scal, float* __restrict__ out) {
  float pos = scal[0];
  float type = scal[1] / fmaxf(scal[2], 1.f) * 10.f;
  out[0] = 0.6f * pos + 0.4f * type;
  out[1] = pos;
  out[2] = type;
}

extern "C" void kernel_launch(void* const* d_in, const int* in_sizes, int n_in,
                              void* d_out, int out_size, void* d_ws, size_t ws_size,
                              hipStream_t stream) {
  const float* hidden = (const float*)d_in[0];
  const int*   amask  = (const int*)d_in[1];
  const int*   plab   = (const int*)d_in[2];
  const int*   tlab   = (const int*)d_in[3];
  const int*   tpos   = (const int*)d_in[4];
  const float* biw    = (const float*)d_in[5];
  const float* Wpos   = (const float*)d_in[6];
  const float* bpos   = (const float*)d_in[7];
  const float* strans = (const float*)d_in[8];
  const float* etrans = (const float*)d_in[9];
  const float* trans  = (const float*)d_in[10];
  const float* W1     = (const float*)d_in[11];
  const float* b1     = (const float*)d_in[12];
  const float* W2     = (const float*)d_in[13];
  const float* b2     = (const float*)d_in[14];
  const float* Wtype  = (const float*)d_in[15];
  const float* btype  = (const float*)d_in[16];
  float* out = (float*)d_out;
  char* ws = (char*)d_ws;

  unsigned short* wt_all  = (unsigned short*)(ws + WT_ALL_OFF);
  unsigned short* wt_type = (unsigned short*)(ws + WT_TYPE_OFF);
  float* em_t    = (float*)(ws + EM_T_OFF);
  float* scores  = (float*)(ws + SCORES_OFF);
  int*   labelsT = (int*)(ws + LABELS_T_OFF);
  int*   lengths = (int*)(ws + LEN_OFF);
  unsigned short* pooled = (unsigned short*)(ws + POOLED_OFF);
  float* logits  = (float*)(ws + LOGITS_OFF);
  float* scal    = (float*)(ws + SCAL_OFF);

  k0_prep<<<1777, 256, 0, stream>>>(W1, Wpos, Wtype, amask, wt_all, wt_type, lengths, scal);
  k1_gemm<<<512, 256, 0, stream>>>(hidden, plab, bpos, b1, W2, b2, biw, wt_all,
                                   em_t, scores, labelsT);
  k2_crf<<<1, 64, 0, stream>>>(em_t, labelsT, lengths, strans, etrans, trans, scal);
  k3_pool<<<512, 64, 0, stream>>>(hidden, scores, tpos, pooled);
  k3b_gemm<<<32, 256, 0, stream>>>(pooled, wt_type, btype, logits);
  k4_focal<<<128, 256, 0, stream>>>(logits, tlab, tpos, scal);
  k5_final<<<1, 1, 0, stream>>>(scal, out);
}

// Round 2
// 140.831 us; speedup vs baseline: 2.0033x; 2.0033x over previous
//
#include <hip/hip_runtime.h>

#define L2E 1.44269504088896340736f
#define LN2 0.69314718055994530942f
#define NEGB -1e30f

typedef float f32x4 __attribute__((ext_vector_type(4)));
typedef __bf16 bf16x8 __attribute__((ext_vector_type(8)));

// problem sizes
static constexpr int NB = 64, NS = 512, NH = 768, NT = 500, NM = 8;

// workspace layout (bytes)
static constexpr size_t WT_ALL_OFF   = 0;        // 80*768 bf16   = 122880
static constexpr size_t WT_TYPE_OFF  = 122880;   // 512*768 bf16  = 786432
static constexpr size_t EM_T_OFF     = 909312;   // 512*3*64 f32  = 393216  (em_t[s][j][b])
static constexpr size_t SCORES_OFF   = 1302528;  // 64*512 f32    = 131072  (scores[b][s])
static constexpr size_t LABELS_T_OFF = 1433600;  // 512*64 i32    = 131072  (labels_t[s][b])
static constexpr size_t LEN_OFF      = 1564672;  // 64 i32
static constexpr size_t POOLED_OFF   = 1564928;  // 512*768 bf16  = 786432
static constexpr size_t LOGITS_OFF   = 2351360;  // 512*512 f32   = 1048576
static constexpr size_t SCAL_OFF     = 3399936;  // 4 f32: [-, focal_sum, v_sum, -]
static constexpr size_t MATM_OFF     = 3400192;  // 64 chunks * 9 * 64 f32 = 147456
static constexpr size_t PSC_OFF      = 3547648;  // 64 chunks * 64 f32     = 16384

__device__ __forceinline__ unsigned short f2bf(float f) {
  unsigned u = __builtin_bit_cast(unsigned, f);
  u += 0x7FFFu + ((u >> 16) & 1u);
  return (unsigned short)(u >> 16);
}
__device__ __forceinline__ float sel3(float a, float b, float c, int i) {
  return i == 0 ? a : (i == 1 ? b : c);
}
__device__ __forceinline__ float lse3(float x, float y, float z) {
  float m = fmaxf(fmaxf(x, y), z);
  float p = exp2f((x - m) * L2E) + exp2f((y - m) * L2E) + exp2f((z - m) * L2E);
  return m + log2f(p) * LN2;
}
__device__ __forceinline__ int swz(int row, int slot) {       // byte addr of 16B slot, XOR-swizzled
  return row * 128 + ((slot ^ (row & 7)) << 4);
}

// ---------------- K0: weight prep (bf16 transposed), lengths, zero accumulators ------------
__global__ __launch_bounds__(256) void k0_prep(
    const float* __restrict__ W1, const float* __restrict__ Wpos,
    const float* __restrict__ Wtype, const int* __restrict__ amask,
    unsigned short* __restrict__ wt_all, unsigned short* __restrict__ wt_type,
    int* __restrict__ lengths, float* __restrict__ scal) {
  __shared__ int part[256];
  int gid = blockIdx.x * 256 + threadIdx.x;
  if (gid < 80 * 768) {                         // wt_all[n][k]: n<64 att_W1 col, 64..66 W_pos col, else 0
    int n = gid / 768, k = gid % 768;
    float v = (n < 64) ? W1[k * 64 + n] : ((n < 67) ? Wpos[k * 3 + (n - 64)] : 0.f);
    wt_all[gid] = f2bf(v);
  } else if (gid < 80 * 768 + 512 * 768) {      // wt_type[n][k], n<500 from W_type col, else 0
    int g = gid - 80 * 768;
    int n = g / 768, k = g % 768;
    float v = (n < 500) ? Wtype[k * 500 + n] : 0.f;
    wt_type[g] = f2bf(v);
  } else {                                       // last block: lengths + scalar zeroing
    int tt = gid - (80 * 768 + 512 * 768);      // 0..255
    int bb = tt >> 2, qq = tt & 3;
    const int4* mp = (const int4*)(amask + bb * 512 + qq * 128);
    int s = 0;
    #pragma unroll 8
    for (int i = 0; i < 32; ++i) { int4 v = mp[i]; s += v.x + v.y + v.z + v.w; }
    part[tt] = s;
    __syncthreads();
    if (qq == 0) lengths[bb] = part[tt] + part[tt + 1] + part[tt + 2] + part[tt + 3];
    if (tt == 0) { scal[1] = 0.f; scal[2] = 0.f; }
  }
}

// ---------------- K1: fused [32768x768]@[768x80] bf16 MFMA + epilogue ------------------------
// cols 0..63 = att pre-act -> tanh*W2 reduce -> scores; cols 64..66 = emissions (weighted)
__global__ __launch_bounds__(256) void k1_gemm(
    const float* __restrict__ hidden, const int* __restrict__ plab,
    const float* __restrict__ bpos, const float* __restrict__ b1,
    const float* __restrict__ W2, const float* __restrict__ b2,
    const float* __restrict__ biw, const unsigned short* __restrict__ wt_all,
    float* __restrict__ em_t, float* __restrict__ scores, int* __restrict__ labels_t) {
  __shared__ char lds[8192 + 10240];
  char* As = lds;            // [64 rows][64 k] bf16, swizzled 16B slots
  char* Bs = lds + 8192;     // [80 n  ][64 k] bf16, swizzled
  const int t = threadIdx.x, w = t >> 6, l = t & 63;
  const int row0 = blockIdx.x * 64;

  f32x4 acc[5];
  #pragma unroll
  for (int nt = 0; nt < 5; ++nt) acc[nt] = (f32x4){0.f, 0.f, 0.f, 0.f};

  for (int it = 0; it < 12; ++it) {
    const int k0 = it * 64;
    // global loads (A fp32, B bf16)
    float4 av[4];
    #pragma unroll
    for (int u = 0; u < 4; ++u) {
      int f4 = t + 256 * u, r = f4 >> 4, k4 = f4 & 15;
      av[u] = *(const float4*)(hidden + (size_t)(row0 + r) * 768 + k0 + 4 * k4);
    }
    uint4 bv0 = *(const uint4*)(wt_all + (t >> 3) * 768 + k0 + 8 * (t & 7));
    uint4 bv1 = *(const uint4*)(wt_all + ((t + 256) >> 3) * 768 + k0 + 8 * (t & 7));
    uint4 bv2 = (t < 128) ? *(const uint4*)(wt_all + ((t + 512) >> 3) * 768 + k0 + 8 * (t & 7))
                          : (uint4){0, 0, 0, 0};
    __syncthreads();   // previous iteration's LDS reads done
    #pragma unroll
    for (int u = 0; u < 4; ++u) {
      int f4 = t + 256 * u, r = f4 >> 4, k4 = f4 & 15;
      unsigned lo = (unsigned)f2bf(av[u].x) | ((unsigned)f2bf(av[u].y) << 16);
      unsigned hi = (unsigned)f2bf(av[u].z) | ((unsigned)f2bf(av[u].w) << 16);
      int byte = r * 128 + (((k4 >> 1) ^ (r & 7)) << 4) + (k4 & 1) * 8;
      *(uint2*)(As + byte) = make_uint2(lo, hi);
    }
    { int n = t >> 3, kc = t & 7;         *(uint4*)(Bs + swz(n, kc)) = bv0; }
    { int n = (t + 256) >> 3, kc = t & 7; *(uint4*)(Bs + swz(n, kc)) = bv1; }
    if (t < 128) { int n = (t + 512) >> 3, kc = t & 7; *(uint4*)(Bs + swz(n, kc)) = bv2; }
    __syncthreads();
    #pragma unroll
    for (int ks = 0; ks < 2; ++ks) {
      int arow = 16 * w + (l & 15);
      int slot = 4 * ks + (l >> 4);
      bf16x8 a = *(const bf16x8*)(As + swz(arow, slot));
      #pragma unroll
      for (int nt = 0; nt < 5; ++nt) {
        int brow = 16 * nt + (l & 15);
        bf16x8 b = *(const bf16x8*)(Bs + swz(brow, slot));
        acc[nt] = __builtin_amdgcn_mfma_f32_16x16x32_bf16(a, b, acc[nt], 0, 0, 0);
      }
    }
  }

  // epilogue: D layout col = l&15 (+16*nt), row = 16*w + 4*(l>>4) + reg
  const int q = l >> 4, c16 = l & 15;
  const float bias2 = b2[0];
  #pragma unroll
  for (int r = 0; r < 4; ++r) {
    float s = 0.f;
    #pragma unroll
    for (int nt = 0; nt < 4; ++nt) {
      int c = 16 * nt + c16;
      float x = acc[nt][r] + b1[c];
      float th = 1.f - 2.f / (1.f + exp2f(x * (2.f * L2E)));
      s += th * W2[c];
    }
    #pragma unroll
    for (int off = 1; off < 16; off <<= 1) s += __shfl_xor(s, off, 64);
    if (c16 == 0) {
      int row = row0 + 16 * w + 4 * q + r;
      scores[row] = s + bias2;
    }
  }
  if (c16 < 3) {
    const float bi = biw[0];
    #pragma unroll
    for (int r = 0; r < 4; ++r) {
      int row = row0 + 16 * w + 4 * q + r;
      int bb = row >> 9, ss = row & 511;
      int lab = plab[row];
      float wgt = (lab > 0) ? 1.f + bi : 1.f;
      float ev = (acc[4][r] + bpos[c16]) * wgt;
      em_t[(ss * 3 + c16) * 64 + bb] = ev;
      if (c16 == 0) labels_t[ss * 64 + bb] = lab;
    }
  }
}

// ---------------- K2a: CRF chunk matrices (log-semiring assoc scan, chunk=8) ----------------
// block c handles steps s in [max(1,8c), 8c+8) for all 64 sequences (lane = seq).
// Produces 3x3 chunk matrix (identity for masked steps) + partial gold score.
__global__ __launch_bounds__(64) void k2a_chunk(
    const float* __restrict__ em_t, const int* __restrict__ labels_t,
    const int* __restrict__ lengths, const float* __restrict__ trans,
    float* __restrict__ matM, float* __restrict__ psc) {
  const int b = threadIdx.x, c = blockIdx.x;
  float T[9];
  #pragma unroll
  for (int i = 0; i < 9; ++i) T[i] = trans[i];
  const int L = lengths[b];
  float M[9];
  #pragma unroll
  for (int i = 0; i < 9; ++i) M[i] = (i == 0 || i == 4 || i == 8) ? 0.f : NEGB;
  float sc = 0.f;
  const int s0 = (c == 0) ? 1 : 8 * c;
  const int s1 = 8 * c + 8;
  int labp = labels_t[(s0 - 1) * 64 + b];
  for (int s = s0; s < s1; ++s) {
    float e0 = em_t[(s * 3 + 0) * 64 + b];
    float e1 = em_t[(s * 3 + 1) * 64 + b];
    float e2 = em_t[(s * 3 + 2) * 64 + b];
    int lab = labels_t[s * 64 + b];
    bool act = s < L;
    float N[9];
    #pragma unroll
    for (int i = 0; i < 3; ++i) {
      float ma = M[3 * i], mb = M[3 * i + 1], mc = M[3 * i + 2];
      N[3 * i + 0] = lse3(ma + T[0], mb + T[3], mc + T[6]) + e0;
      N[3 * i + 1] = lse3(ma + T[1], mb + T[4], mc + T[7]) + e1;
      N[3 * i + 2] = lse3(ma + T[2], mb + T[5], mc + T[8]) + e2;
    }
    #pragma unroll
    for (int i = 0; i < 9; ++i) M[i] = act ? N[i] : M[i];
    float ev = sel3(e0, e1, e2, lab);
    sc += act ? (ev + T[3 * labp + lab]) : 0.f;
    labp = lab;
  }
  #pragma unroll
  for (int i = 0; i < 9; ++i) matM[(c * 9 + i) * 64 + b] = M[i];
  psc[c * 64 + b] = sc;
}

// ---------------- K3: span softmax-pooling, one wave per (b,m) span --------------------------
__global__ __launch_bounds__(64) void k3_pool(
    const float* __restrict__ hidden, const float* __restrict__ scores,
    const int* __restrict__ tpos, unsigned short* __restrict__ pooled) {
  const int span = blockIdx.x, l = threadIdx.x;
  const int b = span >> 3;
  const int st = tpos[span * 2], en = tpos[span * 2 + 1];
  int len = (st + en > 0) ? (en - st) : 0;      // invalid -> 0 -> pooled = 0
  float sv[7], aw[7];
  float wm = -1e30f;
  #pragma unroll
  for (int j = 0; j < 7; ++j) {
    sv[j] = (j < len) ? scores[b * 512 + st + j] : -1e30f;
    wm = fmaxf(wm, sv[j]);
  }
  float den = 0.f;
  #pragma unroll
  for (int j = 0; j < 7; ++j) {
    aw[j] = (j < len) ? exp2f((sv[j] - wm) * L2E) : 0.f;
    den += aw[j];
  }
  float inv = (den > 0.f) ? 1.f / den : 0.f;
  #pragma unroll
  for (int j = 0; j < 7; ++j) aw[j] *= inv;
  #pragma unroll
  for (int r = 0; r < 12; ++r) {
    int h = l + 64 * r;
    float acc = 0.f;
    #pragma unroll
    for (int j = 0; j < 7; ++j)
      if (j < len) acc += aw[j] * hidden[(size_t)(b * 512 + st + j) * 768 + h];
    pooled[span * 768 + h] = f2bf(acc);
  }
}

// ---------------- K3b: [512x768]@[768x512(500 pad)] bf16 MFMA -> logits ----------------------
__global__ __launch_bounds__(256) void k3b_gemm(
    const unsigned short* __restrict__ pooled, const unsigned short* __restrict__ wt_type,
    const float* __restrict__ btype, float* __restrict__ logits) {
  __shared__ char lds[8192 + 16384];
  char* As = lds;           // [64][64] bf16 swizzled
  char* Bs = lds + 8192;    // [128][64] bf16 swizzled
  const int t = threadIdx.x, w = t >> 6, l = t & 63;
  const int row0 = (blockIdx.x >> 2) * 64, n0 = (blockIdx.x & 3) * 128;

  f32x4 acc[8];
  #pragma unroll
  for (int nt = 0; nt < 8; ++nt) acc[nt] = (f32x4){0.f, 0.f, 0.f, 0.f};

  for (int it = 0; it < 12; ++it) {
    const int k0 = it * 64;
    uint4 av[2], bvv[4];
    #pragma unroll
    for (int u = 0; u < 2; ++u) {
      int idx = t + 256 * u, r = idx >> 3, kc = idx & 7;
      av[u] = *(const uint4*)(pooled + (size_t)(row0 + r) * 768 + k0 + 8 * kc);
    }
    #pragma unroll
    for (int u = 0; u < 4; ++u) {
      int idx = t + 256 * u, n = idx >> 3, kc = idx & 7;
      bvv[u] = *(const uint4*)(wt_type + (size_t)(n0 + n) * 768 + k0 + 8 * kc);
    }
    __syncthreads();
    #pragma unroll
    for (int u = 0; u < 2; ++u) {
      int idx = t + 256 * u, r = idx >> 3, kc = idx & 7;
      *(uint4*)(As + swz(r, kc)) = av[u];
    }
    #pragma unroll
    for (int u = 0; u < 4; ++u) {
      int idx = t + 256 * u, n = idx >> 3, kc = idx & 7;
      *(uint4*)(Bs + swz(n, kc)) = bvv[u];
    }
    __syncthreads();
    #pragma unroll
    for (int ks = 0; ks < 2; ++ks) {
      int arow = 16 * w + (l & 15);
      int slot = 4 * ks + (l >> 4);
      bf16x8 a = *(const bf16x8*)(As + swz(arow, slot));
      #pragma unroll
      for (int nt = 0; nt < 8; ++nt) {
        int brow = 16 * nt + (l & 15);
        bf16x8 b = *(const bf16x8*)(Bs + swz(brow, slot));
        acc[nt] = __builtin_amdgcn_mfma_f32_16x16x32_bf16(a, b, acc[nt], 0, 0, 0);
      }
    }
  }
  const int q = l >> 4, c16 = l & 15;
  #pragma unroll
  for (int nt = 0; nt < 8; ++nt) {
    int col = n0 + 16 * nt + c16;
    #pragma unroll
    for (int r = 0; r < 4; ++r) {
      int row = row0 + 16 * w + 4 * q + r;
      float v = (col < 500) ? acc[nt][r] + btype[col] : -1e30f;
      logits[row * 512 + col] = v;
    }
  }
}

// ---------------- K4: per-span label-smoothed focal CE, atomic accumulate --------------------
__global__ __launch_bounds__(256) void k4_focal(
    const float* __restrict__ logits, const int* __restrict__ tlab,
    const int* __restrict__ tpos, float* __restrict__ scal) {
  const int w = threadIdx.x >> 6, l = threadIdx.x & 63;
  const int row = blockIdx.x * 4 + w;
  float v[8];
  #pragma unroll
  for (int j = 0; j < 8; ++j) v[j] = logits[row * 512 + l + 64 * j];
  float m = v[0];
  #pragma unroll
  for (int j = 1; j < 8; ++j) m = fmaxf(m, v[j]);
  #pragma unroll
  for (int off = 1; off < 64; off <<= 1) m = fmaxf(m, __shfl_xor(m, off, 64));
  float p = 0.f, slog = 0.f;
  #pragma unroll
  for (int j = 0; j < 8; ++j) {
    p += exp2f((v[j] - m) * L2E);                 // padded cols are -1e30 -> 0
    slog += (l + 64 * j < 500) ? v[j] : 0.f;
  }
  #pragma unroll
  for (int off = 1; off < 64; off <<= 1) {
    p += __shfl_xor(p, off, 64);
    slog += __shfl_xor(slog, off, 64);
  }
  float logZ = m + log2f(p) * LN2;
  int lbl = tlab[row];
  float vl = logits[row * 512 + lbl];
  float lp = vl - logZ;
  float ce = -(0.9f * lp + 2e-4f * (slog - 500.f * logZ));
  float pt = 0.9f * exp2f(lp * L2E) + 2e-4f;
  float focal = ce * (1.f - pt) * (1.f - pt);
  bool valid = (tpos[row * 2] + tpos[row * 2 + 1]) > 0;
  if (l == 0 && valid) {
    atomicAdd(&scal[1], focal);
    atomicAdd(&scal[2], 1.f);
  }
}

// ---------------- K_final: CRF chunk-scan (alpha through 64 chunk matrices) + combine --------
__global__ __launch_bounds__(64) void k_final(
    const float* __restrict__ em_t, const int* __restrict__ labels_t,
    const int* __restrict__ lengths, const float* __restrict__ strans,
    const float* __restrict__ etrans, const float* __restrict__ matM,
    const float* __restrict__ psc, const float* __restrict__ scal,
    float* __restrict__ out) {
  const int b = threadIdx.x;
  const int L = lengths[b];
  const float st0 = strans[0], st1 = strans[1], st2 = strans[2];
  const float et0 = etrans[0], et1 = etrans[1], et2 = etrans[2];
  float e00 = em_t[0 * 64 + b], e01 = em_t[1 * 64 + b], e02 = em_t[2 * 64 + b];
  int lab0 = labels_t[b];
  float a0 = st0 + e00, a1 = st1 + e01, a2 = st2 + e02;
  float score = sel3(st0, st1, st2, lab0) + sel3(e00, e01, e02, lab0);
  for (int c = 0; c < 64; ++c) {
    const float* mp = matM + c * 9 * 64 + b;
    float m0 = mp[0 * 64], m1 = mp[1 * 64], m2 = mp[2 * 64];
    float m3 = mp[3 * 64], m4 = mp[4 * 64], m5 = mp[5 * 64];
    float m6 = mp[6 * 64], m7 = mp[7 * 64], m8 = mp[8 * 64];
    float n0 = lse3(a0 + m0, a1 + m3, a2 + m6);
    float n1 = lse3(a0 + m1, a1 + m4, a2 + m7);
    float n2 = lse3(a0 + m2, a1 + m5, a2 + m8);
    a0 = n0; a1 = n1; a2 = n2;
    score += psc[c * 64 + b];
  }
  int last = labels_t[(L - 1) * 64 + b];
  score += sel3(et0, et1, et2, last);
  float logZ = lse3(a0 + et0, a1 + et1, a2 + et2);
  float nll = logZ - score;
  #pragma unroll
  for (int off = 1; off < 64; off <<= 1) nll += __shfl_xor(nll, off, 64);
  if (b == 0) {
    float pos = nll / 64.f;
    float type = scal[1] / fmaxf(scal[2], 1.f) * 10.f;
    out[0] = 0.6f * pos + 0.4f * type;
    out[1] = pos;
    out[2] = type;
  }
}

extern "C" void kernel_launch(void* const* d_in, const int* in_sizes, int n_in,
                              void* d_out, int out_size, void* d_ws, size_t ws_size,
                              hipStream_t stream) {
  const float* hidden = (const float*)d_in[0];
  const int*   amask  = (const int*)d_in[1];
  const int*   plab   = (const int*)d_in[2];
  const int*   tlab   = (const int*)d_in[3];
  const int*   tpos   = (const int*)d_in[4];
  const float* biw    = (const float*)d_in[5];
  const float* Wpos   = (const float*)d_in[6];
  const float* bpos   = (const float*)d_in[7];
  const float* strans = (const float*)d_in[8];
  const float* etrans = (const float*)d_in[9];
  const float* trans  = (const float*)d_in[10];
  const float* W1     = (const float*)d_in[11];
  const float* b1     = (const float*)d_in[12];
  const float* W2     = (const float*)d_in[13];
  const float* b2     = (const float*)d_in[14];
  const float* Wtype  = (const float*)d_in[15];
  const float* btype  = (const float*)d_in[16];
  float* out = (float*)d_out;
  char* ws = (char*)d_ws;

  unsigned short* wt_all  = (unsigned short*)(ws + WT_ALL_OFF);
  unsigned short* wt_type = (unsigned short*)(ws + WT_TYPE_OFF);
  float* em_t    = (float*)(ws + EM_T_OFF);
  float* scores  = (float*)(ws + SCORES_OFF);
  int*   labelsT = (int*)(ws + LABELS_T_OFF);
  int*   lengths = (int*)(ws + LEN_OFF);
  unsigned short* pooled = (unsigned short*)(ws + POOLED_OFF);
  float* logits  = (float*)(ws + LOGITS_OFF);
  float* scal    = (float*)(ws + SCAL_OFF);
  float* matM    = (float*)(ws + MATM_OFF);
  float* psc     = (float*)(ws + PSC_OFF);

  k0_prep<<<1777, 256, 0, stream>>>(W1, Wpos, Wtype, amask, wt_all, wt_type, lengths, scal);
  k1_gemm<<<512, 256, 0, stream>>>(hidden, plab, bpos, b1, W2, b2, biw, wt_all,
                                   em_t, scores, labelsT);
  k2a_chunk<<<64, 64, 0, stream>>>(em_t, labelsT, lengths, trans, matM, psc);
  k3_pool<<<512, 64, 0, stream>>>(hidden, scores, tpos, pooled);
  k3b_gemm<<<32, 256, 0, stream>>>(pooled, wt_type, btype, logits);
  k4_focal<<<128, 256, 0, stream>>>(logits, tlab, tpos, scal);
  k_final<<<1, 64, 0, stream>>>(em_t, labelsT, lengths, strans, etrans, matM, psc, scal, out);
}

// Round 3
// 125.407 us; speedup vs baseline: 2.2496x; 1.1230x over previous
//
#include <hip/hip_runtime.h>

#define L2E 1.44269504088896340736f
#define LN2 0.69314718055994530942f
#define NEGB -1e30f

typedef float f32x4 __attribute__((ext_vector_type(4)));
typedef __bf16 bf16x8 __attribute__((ext_vector_type(8)));

// problem sizes
static constexpr int NB = 64, NS = 512, NH = 768, NT = 500, NM = 8;

// workspace layout (bytes)
static constexpr size_t WT_ALL_OFF   = 0;        // 80*768 bf16   = 122880
static constexpr size_t WT_TYPE_OFF  = 122880;   // 512*768 bf16  = 786432
static constexpr size_t EM_T_OFF     = 909312;   // 512*3*64 f32  = 393216  (em_t[s][j][b])
static constexpr size_t SCORES_OFF   = 1302528;  // 64*512 f32    = 131072  (scores[b][s])
static constexpr size_t LABELS_T_OFF = 1433600;  // 512*64 i32    = 131072  (labels_t[s][b])
static constexpr size_t LEN_OFF      = 1564672;  // 64 i32
static constexpr size_t POOLED_OFF   = 1564928;  // 512*768 bf16  = 786432
static constexpr size_t LOGITS_OFF   = 2351360;  // 512*512 f32   = 1048576
static constexpr size_t SCAL_OFF     = 3399936;  // 4 f32: [-, focal_sum, v_sum, -]
static constexpr size_t MATM_OFF     = 3400192;  // 64 chunks * 9 * 64 f32 = 147456
static constexpr size_t PSC_OFF      = 3547648;  // 64 chunks * 64 f32     = 16384

__device__ __forceinline__ unsigned short f2bf(float f) {
  unsigned u = __builtin_bit_cast(unsigned, f);
  u += 0x7FFFu + ((u >> 16) & 1u);
  return (unsigned short)(u >> 16);
}
__device__ __forceinline__ float sel3(float a, float b, float c, int i) {
  return i == 0 ? a : (i == 1 ? b : c);
}
__device__ __forceinline__ float lse3(float x, float y, float z) {
  float m = fmaxf(fmaxf(x, y), z);
  float p = exp2f((x - m) * L2E) + exp2f((y - m) * L2E) + exp2f((z - m) * L2E);
  return m + log2f(p) * LN2;
}
__device__ __forceinline__ int swz(int row, int slot) {       // byte addr of 16B slot, XOR-swizzled
  return row * 128 + ((slot ^ (row & 7)) << 4);
}

// ---------------- K0: weight prep (bf16 transposed), lengths, zero accumulators ------------
__global__ __launch_bounds__(256) void k0_prep(
    const float* __restrict__ W1, const float* __restrict__ Wpos,
    const float* __restrict__ Wtype, const int* __restrict__ amask,
    unsigned short* __restrict__ wt_all, unsigned short* __restrict__ wt_type,
    int* __restrict__ lengths, float* __restrict__ scal) {
  __shared__ int part[256];
  int gid = blockIdx.x * 256 + threadIdx.x;
  if (gid < 80 * 768) {                         // wt_all[n][k]: n<64 att_W1 col, 64..66 W_pos col, else 0
    int n = gid / 768, k = gid % 768;
    float v = (n < 64) ? W1[k * 64 + n] : ((n < 67) ? Wpos[k * 3 + (n - 64)] : 0.f);
    wt_all[gid] = f2bf(v);
  } else if (gid < 80 * 768 + 512 * 768) {      // wt_type[n][k], n<500 from W_type col, else 0
    int g = gid - 80 * 768;
    int n = g / 768, k = g % 768;
    float v = (n < 500) ? Wtype[k * 500 + n] : 0.f;
    wt_type[g] = f2bf(v);
  } else {                                       // last block: lengths + scalar zeroing
    int tt = gid - (80 * 768 + 512 * 768);      // 0..255
    int bb = tt >> 2, qq = tt & 3;
    const int4* mp = (const int4*)(amask + bb * 512 + qq * 128);
    int s = 0;
    #pragma unroll 8
    for (int i = 0; i < 32; ++i) { int4 v = mp[i]; s += v.x + v.y + v.z + v.w; }
    part[tt] = s;
    __syncthreads();
    if (qq == 0) lengths[bb] = part[tt] + part[tt + 1] + part[tt + 2] + part[tt + 3];
    if (tt == 0) { scal[1] = 0.f; scal[2] = 0.f; }
  }
}

// ---------------- K1: fused [32768x768]@[768x80] bf16 MFMA + epilogue, reg-prefetch ----------
// cols 0..63 = att pre-act -> tanh*W2 reduce -> scores; cols 64..66 = emissions (weighted)
__global__ __launch_bounds__(256) void k1_gemm(
    const float* __restrict__ hidden, const int* __restrict__ plab,
    const float* __restrict__ bpos, const float* __restrict__ b1,
    const float* __restrict__ W2, const float* __restrict__ b2,
    const float* __restrict__ biw, const unsigned short* __restrict__ wt_all,
    float* __restrict__ em_t, float* __restrict__ scores, int* __restrict__ labels_t) {
  __shared__ char lds[8192 + 10240];
  char* As = lds;            // [64 rows][64 k] bf16, swizzled 16B slots
  char* Bs = lds + 8192;     // [80 n  ][64 k] bf16, swizzled
  const int t = threadIdx.x, w = t >> 6, l = t & 63;
  const int row0 = blockIdx.x * 64;

  f32x4 acc[5];
  #pragma unroll
  for (int nt = 0; nt < 5; ++nt) acc[nt] = (f32x4){0.f, 0.f, 0.f, 0.f};

  auto loadAB = [&](int it, float4 av[4], uint4 bv[3]) {
    const int k0 = it * 64;
    #pragma unroll
    for (int u = 0; u < 4; ++u) {
      int f4 = t + 256 * u, r = f4 >> 4, k4 = f4 & 15;
      av[u] = *(const float4*)(hidden + (size_t)(row0 + r) * 768 + k0 + 4 * k4);
    }
    bv[0] = *(const uint4*)(wt_all + (t >> 3) * 768 + k0 + 8 * (t & 7));
    bv[1] = *(const uint4*)(wt_all + ((t + 256) >> 3) * 768 + k0 + 8 * (t & 7));
    bv[2] = (t < 128) ? *(const uint4*)(wt_all + ((t + 512) >> 3) * 768 + k0 + 8 * (t & 7))
                      : (uint4){0, 0, 0, 0};
  };

  float4 avc[4]; uint4 bvc[3];
  loadAB(0, avc, bvc);

  for (int it = 0; it < 12; ++it) {
    __syncthreads();   // previous iteration's LDS reads done
    #pragma unroll
    for (int u = 0; u < 4; ++u) {
      int f4 = t + 256 * u, r = f4 >> 4, k4 = f4 & 15;
      unsigned lo = (unsigned)f2bf(avc[u].x) | ((unsigned)f2bf(avc[u].y) << 16);
      unsigned hi = (unsigned)f2bf(avc[u].z) | ((unsigned)f2bf(avc[u].w) << 16);
      int byte = r * 128 + (((k4 >> 1) ^ (r & 7)) << 4) + (k4 & 1) * 8;
      *(uint2*)(As + byte) = make_uint2(lo, hi);
    }
    { int n = t >> 3, kc = t & 7;         *(uint4*)(Bs + swz(n, kc)) = bvc[0]; }
    { int n = (t + 256) >> 3, kc = t & 7; *(uint4*)(Bs + swz(n, kc)) = bvc[1]; }
    if (t < 128) { int n = (t + 512) >> 3, kc = t & 7; *(uint4*)(Bs + swz(n, kc)) = bvc[2]; }
    __syncthreads();

    float4 avn[4]; uint4 bvn[3];
    if (it < 11) loadAB(it + 1, avn, bvn);     // prefetch next tile during MFMA phase

    #pragma unroll
    for (int ks = 0; ks < 2; ++ks) {
      int arow = 16 * w + (l & 15);
      int slot = 4 * ks + (l >> 4);
      bf16x8 a = *(const bf16x8*)(As + swz(arow, slot));
      #pragma unroll
      for (int nt = 0; nt < 5; ++nt) {
        int brow = 16 * nt + (l & 15);
        bf16x8 b = *(const bf16x8*)(Bs + swz(brow, slot));
        acc[nt] = __builtin_amdgcn_mfma_f32_16x16x32_bf16(a, b, acc[nt], 0, 0, 0);
      }
    }
    if (it < 11) {
      #pragma unroll
      for (int u = 0; u < 4; ++u) avc[u] = avn[u];
      #pragma unroll
      for (int u = 0; u < 3; ++u) bvc[u] = bvn[u];
    }
  }

  // epilogue: D layout col = l&15 (+16*nt), row = 16*w + 4*(l>>4) + reg
  const int q = l >> 4, c16 = l & 15;
  const float bias2 = b2[0];
  #pragma unroll
  for (int r = 0; r < 4; ++r) {
    float s = 0.f;
    #pragma unroll
    for (int nt = 0; nt < 4; ++nt) {
      int c = 16 * nt + c16;
      float x = acc[nt][r] + b1[c];
      float th = 1.f - 2.f / (1.f + exp2f(x * (2.f * L2E)));
      s += th * W2[c];
    }
    #pragma unroll
    for (int off = 1; off < 16; off <<= 1) s += __shfl_xor(s, off, 64);
    if (c16 == 0) {
      int row = row0 + 16 * w + 4 * q + r;
      scores[row] = s + bias2;
    }
  }
  if (c16 < 3) {
    const float bi = biw[0];
    #pragma unroll
    for (int r = 0; r < 4; ++r) {
      int row = row0 + 16 * w + 4 * q + r;
      int bb = row >> 9, ss = row & 511;
      int lab = plab[row];
      float wgt = (lab > 0) ? 1.f + bi : 1.f;
      float ev = (acc[4][r] + bpos[c16]) * wgt;
      em_t[(ss * 3 + c16) * 64 + bb] = ev;
      if (c16 == 0) labels_t[ss * 64 + bb] = lab;
    }
  }
}

// ---------------- K2a: CRF chunk matrices (log-semiring assoc scan, chunk=8) ----------------
// block c handles steps s in [8c, 8c+8) (s=0 inactive) for all 64 sequences (lane = seq).
// All loads batched upfront; static indexing throughout.
__global__ __launch_bounds__(64) void k2a_chunk(
    const float* __restrict__ em_t, const int* __restrict__ labels_t,
    const int* __restrict__ lengths, const float* __restrict__ trans,
    float* __restrict__ matM, float* __restrict__ psc) {
  const int b = threadIdx.x, c = blockIdx.x;
  float T0 = trans[0], T1 = trans[1], T2 = trans[2];
  float T3 = trans[3], T4 = trans[4], T5 = trans[5];
  float T6 = trans[6], T7 = trans[7], T8 = trans[8];
  const int L = lengths[b];
  const int s0 = 8 * c;
  int labp = labels_t[(c ? (s0 - 1) : 0) * 64 + b];

  float E0[8], E1[8], E2[8]; int LB[8];
  #pragma unroll
  for (int i = 0; i < 8; ++i) {
    E0[i] = em_t[((s0 + i) * 3 + 0) * 64 + b];
    E1[i] = em_t[((s0 + i) * 3 + 1) * 64 + b];
    E2[i] = em_t[((s0 + i) * 3 + 2) * 64 + b];
    LB[i] = labels_t[(s0 + i) * 64 + b];
  }

  float M[9];
  #pragma unroll
  for (int i = 0; i < 9; ++i) M[i] = (i == 0 || i == 4 || i == 8) ? 0.f : NEGB;
  float sc = 0.f;

  #pragma unroll
  for (int i = 0; i < 8; ++i) {
    int s = s0 + i;
    bool act = (s >= 1) && (s < L);
    float N[9];
    #pragma unroll
    for (int r = 0; r < 3; ++r) {
      float ma = M[3 * r], mb = M[3 * r + 1], mc = M[3 * r + 2];
      N[3 * r + 0] = lse3(ma + T0, mb + T3, mc + T6) + E0[i];
      N[3 * r + 1] = lse3(ma + T1, mb + T4, mc + T7) + E1[i];
      N[3 * r + 2] = lse3(ma + T2, mb + T5, mc + T8) + E2[i];
    }
    #pragma unroll
    for (int r = 0; r < 9; ++r) M[r] = act ? N[r] : M[r];
    int lab = LB[i];
    float ev = sel3(E0[i], E1[i], E2[i], lab);
    float trv = sel3(sel3(T0, T1, T2, lab),
                     sel3(T3, T4, T5, lab),
                     sel3(T6, T7, T8, lab), labp);
    sc += act ? (ev + trv) : 0.f;
    labp = lab;
  }
  #pragma unroll
  for (int i = 0; i < 9; ++i) matM[(c * 9 + i) * 64 + b] = M[i];
  psc[c * 64 + b] = sc;
}

// ---------------- K3: span softmax-pooling, one wave per (b,m) span --------------------------
__global__ __launch_bounds__(64) void k3_pool(
    const float* __restrict__ hidden, const float* __restrict__ scores,
    const int* __restrict__ tpos, unsigned short* __restrict__ pooled) {
  const int span = blockIdx.x, l = threadIdx.x;
  const int b = span >> 3;
  const int st = tpos[span * 2], en = tpos[span * 2 + 1];
  int len = (st + en > 0) ? (en - st) : 0;      // invalid -> 0 -> pooled = 0
  float sv[7], aw[7];
  float wm = -1e30f;
  #pragma unroll
  for (int j = 0; j < 7; ++j) {
    sv[j] = (j < len) ? scores[b * 512 + st + j] : -1e30f;
    wm = fmaxf(wm, sv[j]);
  }
  float den = 0.f;
  #pragma unroll
  for (int j = 0; j < 7; ++j) {
    aw[j] = (j < len) ? exp2f((sv[j] - wm) * L2E) : 0.f;
    den += aw[j];
  }
  float inv = (den > 0.f) ? 1.f / den : 0.f;
  #pragma unroll
  for (int j = 0; j < 7; ++j) aw[j] *= inv;
  #pragma unroll
  for (int r = 0; r < 12; ++r) {
    int h = l + 64 * r;
    float acc = 0.f;
    #pragma unroll
    for (int j = 0; j < 7; ++j)
      if (j < len) acc += aw[j] * hidden[(size_t)(b * 512 + st + j) * 768 + h];
    pooled[span * 768 + h] = f2bf(acc);
  }
}

// ---------------- K3b: [512x768]@[768x512(500 pad)] bf16 MFMA -> logits, 64 blocks -----------
__global__ __launch_bounds__(256) void k3b_gemm(
    const unsigned short* __restrict__ pooled, const unsigned short* __restrict__ wt_type,
    const float* __restrict__ btype, float* __restrict__ logits) {
  __shared__ char lds[8192 + 8192];
  char* As = lds;           // [64][64] bf16 swizzled
  char* Bs = lds + 8192;    // [64][64] bf16 swizzled
  const int t = threadIdx.x, w = t >> 6, l = t & 63;
  const int row0 = (blockIdx.x >> 3) * 64, n0 = (blockIdx.x & 7) * 64;

  f32x4 acc[4];
  #pragma unroll
  for (int nt = 0; nt < 4; ++nt) acc[nt] = (f32x4){0.f, 0.f, 0.f, 0.f};

  auto loadAB = [&](int it, uint4 av[2], uint4 bv[2]) {
    const int k0 = it * 64;
    #pragma unroll
    for (int u = 0; u < 2; ++u) {
      int idx = t + 256 * u, r = idx >> 3, kc = idx & 7;
      av[u] = *(const uint4*)(pooled + (size_t)(row0 + r) * 768 + k0 + 8 * kc);
      bv[u] = *(const uint4*)(wt_type + (size_t)(n0 + r) * 768 + k0 + 8 * kc);
    }
  };

  uint4 avc[2], bvc[2];
  loadAB(0, avc, bvc);

  for (int it = 0; it < 12; ++it) {
    __syncthreads();
    #pragma unroll
    for (int u = 0; u < 2; ++u) {
      int idx = t + 256 * u, r = idx >> 3, kc = idx & 7;
      *(uint4*)(As + swz(r, kc)) = avc[u];
      *(uint4*)(Bs + swz(r, kc)) = bvc[u];
    }
    __syncthreads();

    uint4 avn[2], bvn[2];
    if (it < 11) loadAB(it + 1, avn, bvn);

    #pragma unroll
    for (int ks = 0; ks < 2; ++ks) {
      int arow = 16 * w + (l & 15);
      int slot = 4 * ks + (l >> 4);
      bf16x8 a = *(const bf16x8*)(As + swz(arow, slot));
      #pragma unroll
      for (int nt = 0; nt < 4; ++nt) {
        int brow = 16 * nt + (l & 15);
        bf16x8 b = *(const bf16x8*)(Bs + swz(brow, slot));
        acc[nt] = __builtin_amdgcn_mfma_f32_16x16x32_bf16(a, b, acc[nt], 0, 0, 0);
      }
    }
    if (it < 11) {
      #pragma unroll
      for (int u = 0; u < 2; ++u) { avc[u] = avn[u]; bvc[u] = bvn[u]; }
    }
  }
  const int q = l >> 4, c16 = l & 15;
  #pragma unroll
  for (int nt = 0; nt < 4; ++nt) {
    int col = n0 + 16 * nt + c16;
    #pragma unroll
    for (int r = 0; r < 4; ++r) {
      int row = row0 + 16 * w + 4 * q + r;
      float v = (col < 500) ? acc[nt][r] + btype[col] : -1e30f;
      logits[row * 512 + col] = v;
    }
  }
}

// ---------------- K4: per-span label-smoothed focal CE, atomic accumulate --------------------
__global__ __launch_bounds__(256) void k4_focal(
    const float* __restrict__ logits, const int* __restrict__ tlab,
    const int* __restrict__ tpos, float* __restrict__ scal) {
  const int w = threadIdx.x >> 6, l = threadIdx.x & 63;
  const int row = blockIdx.x * 4 + w;
  float v[8];
  #pragma unroll
  for (int j = 0; j < 8; ++j) v[j] = logits[row * 512 + l + 64 * j];
  float m = v[0];
  #pragma unroll
  for (int j = 1; j < 8; ++j) m = fmaxf(m, v[j]);
  #pragma unroll
  for (int off = 1; off < 64; off <<= 1) m = fmaxf(m, __shfl_xor(m, off, 64));
  float p = 0.f, slog = 0.f;
  #pragma unroll
  for (int j = 0; j < 8; ++j) {
    p += exp2f((v[j] - m) * L2E);                 // padded cols are -1e30 -> 0
    slog += (l + 64 * j < 500) ? v[j] : 0.f;
  }
  #pragma unroll
  for (int off = 1; off < 64; off <<= 1) {
    p += __shfl_xor(p, off, 64);
    slog += __shfl_xor(slog, off, 64);
  }
  float logZ = m + log2f(p) * LN2;
  int lbl = tlab[row];
  float vl = logits[row * 512 + lbl];
  float lp = vl - logZ;
  float ce = -(0.9f * lp + 2e-4f * (slog - 500.f * logZ));
  float pt = 0.9f * exp2f(lp * L2E) + 2e-4f;
  float focal = ce * (1.f - pt) * (1.f - pt);
  bool valid = (tpos[row * 2] + tpos[row * 2 + 1]) > 0;
  if (l == 0 && valid) {
    atomicAdd(&scal[1], focal);
    atomicAdd(&scal[2], 1.f);
  }
}

// ---------------- K_final: CRF chunk-scan, 8-chunk banked prefetch + combine -----------------
__global__ __launch_bounds__(64) void k_final(
    const float* __restrict__ em_t, const int* __restrict__ labels_t,
    const int* __restrict__ lengths, const float* __restrict__ strans,
    const float* __restrict__ etrans, const float* __restrict__ matM,
    const float* __restrict__ psc, const float* __restrict__ scal,
    float* __restrict__ out) {
  const int b = threadIdx.x;
  const int L = lengths[b];
  const float st0 = strans[0], st1 = strans[1], st2 = strans[2];
  const float et0 = etrans[0], et1 = etrans[1], et2 = etrans[2];
  float e00 = em_t[0 * 64 + b], e01 = em_t[1 * 64 + b], e02 = em_t[2 * 64 + b];
  int lab0 = labels_t[b];
  float a0 = st0 + e00, a1 = st1 + e01, a2 = st2 + e02;
  float score = sel3(st0, st1, st2, lab0) + sel3(e00, e01, e02, lab0);

  float cur[8][10];
  #pragma unroll
  for (int j = 0; j < 8; ++j) {
    #pragma unroll
    for (int i = 0; i < 9; ++i) cur[j][i] = matM[(j * 9 + i) * 64 + b];
    cur[j][9] = psc[j * 64 + b];
  }

  #pragma unroll
  for (int r = 0; r < 8; ++r) {
    float nxt[8][10];
    if (r < 7) {
      #pragma unroll
      for (int j = 0; j < 8; ++j) {
        int c = (r + 1) * 8 + j;
        #pragma unroll
        for (int i = 0; i < 9; ++i) nxt[j][i] = matM[(c * 9 + i) * 64 + b];
        nxt[j][9] = psc[c * 64 + b];
      }
    }
    #pragma unroll
    for (int j = 0; j < 8; ++j) {
      float n0 = lse3(a0 + cur[j][0], a1 + cur[j][3], a2 + cur[j][6]);
      float n1 = lse3(a0 + cur[j][1], a1 + cur[j][4], a2 + cur[j][7]);
      float n2 = lse3(a0 + cur[j][2], a1 + cur[j][5], a2 + cur[j][8]);
      a0 = n0; a1 = n1; a2 = n2;
      score += cur[j][9];
    }
    if (r < 7) {
      #pragma unroll
      for (int j = 0; j < 8; ++j)
        #pragma unroll
        for (int i = 0; i < 10; ++i) cur[j][i] = nxt[j][i];
    }
  }

  int last = labels_t[(L - 1) * 64 + b];
  score += sel3(et0, et1, et2, last);
  float logZ = lse3(a0 + et0, a1 + et1, a2 + et2);
  float nll = logZ - score;
  #pragma unroll
  for (int off = 1; off < 64; off <<= 1) nll += __shfl_xor(nll, off, 64);
  if (b == 0) {
    float pos = nll / 64.f;
    float type = scal[1] / fmaxf(scal[2], 1.f) * 10.f;
    out[0] = 0.6f * pos + 0.4f * type;
    out[1] = pos;
    out[2] = type;
  }
}

extern "C" void kernel_launch(void* const* d_in, const int* in_sizes, int n_in,
                              void* d_out, int out_size, void* d_ws, size_t ws_size,
                              hipStream_t stream) {
  const float* hidden = (const float*)d_in[0];
  const int*   amask  = (const int*)d_in[1];
  const int*   plab   = (const int*)d_in[2];
  const int*   tlab   = (const int*)d_in[3];
  const int*   tpos   = (const int*)d_in[4];
  const float* biw    = (const float*)d_in[5];
  const float* Wpos   = (const float*)d_in[6];
  const float* bpos   = (const float*)d_in[7];
  const float* strans = (const float*)d_in[8];
  const float* etrans = (const float*)d_in[9];
  const float* trans  = (const float*)d_in[10];
  const float* W1     = (const float*)d_in[11];
  const float* b1     = (const float*)d_in[12];
  const float* W2     = (const float*)d_in[13];
  const float* b2     = (const float*)d_in[14];
  const float* Wtype  = (const float*)d_in[15];
  const float* btype  = (const float*)d_in[16];
  float* out = (float*)d_out;
  char* ws = (char*)d_ws;

  unsigned short* wt_all  = (unsigned short*)(ws + WT_ALL_OFF);
  unsigned short* wt_type = (unsigned short*)(ws + WT_TYPE_OFF);
  float* em_t    = (float*)(ws + EM_T_OFF);
  float* scores  = (float*)(ws + SCORES_OFF);
  int*   labelsT = (int*)(ws + LABELS_T_OFF);
  int*   lengths = (int*)(ws + LEN_OFF);
  unsigned short* pooled = (unsigned short*)(ws + POOLED_OFF);
  float* logits  = (float*)(ws + LOGITS_OFF);
  float* scal    = (float*)(ws + SCAL_OFF);
  float* matM    = (float*)(ws + MATM_OFF);
  float* psc     = (float*)(ws + PSC_OFF);

  k0_prep<<<1777, 256, 0, stream>>>(W1, Wpos, Wtype, amask, wt_all, wt_type, lengths, scal);
  k1_gemm<<<512, 256, 0, stream>>>(hidden, plab, bpos, b1, W2, b2, biw, wt_all,
                                   em_t, scores, labelsT);
  k2a_chunk<<<64, 64, 0, stream>>>(em_t, labelsT, lengths, trans, matM, psc);
  k3_pool<<<512, 64, 0, stream>>>(hidden, scores, tpos, pooled);
  k3b_gemm<<<64, 256, 0, stream>>>(pooled, wt_type, btype, logits);
  k4_focal<<<128, 256, 0, stream>>>(logits, tlab, tpos, scal);
  k_final<<<1, 64, 0, stream>>>(em_t, labelsT, lengths, strans, etrans, matM, psc, scal, out);
}

// Round 4
// 104.249 us; speedup vs baseline: 2.7062x; 1.2029x over previous
//
#include <hip/hip_runtime.h>

#define L2E 1.44269504088896340736f
#define LN2 0.69314718055994530942f
#define NEGB -1e30f

typedef float f32x4 __attribute__((ext_vector_type(4)));
typedef __bf16 bf16x8 __attribute__((ext_vector_type(8)));

// problem sizes
static constexpr int NB = 64, NS = 512, NH = 768, NT = 500, NM = 8;

// workspace layout (bytes)
static constexpr size_t WT_ALL_OFF   = 0;        // 80*768 bf16   = 122880
static constexpr size_t WT_TYPE_OFF  = 122880;   // 512*768 bf16  = 786432
static constexpr size_t EM_T_OFF     = 909312;   // 512*3*64 f32  = 393216  (em_t[s][j][b])
static constexpr size_t SCORES_OFF   = 1302528;  // 64*512 f32    = 131072  (scores[b][s])
static constexpr size_t LABELS_T_OFF = 1433600;  // 512*64 i32    = 131072  (labels_t[s][b])
static constexpr size_t LEN_OFF      = 1564672;  // 64 i32
static constexpr size_t SCAL_OFF     = 3399936;  // 4 f32: [-, focal_sum, v_sum, -]
static constexpr size_t MATM_OFF     = 3400192;  // 64 chunks * 9 * 64 f32 = 147456
static constexpr size_t PSC_OFF      = 3547648;  // 64 chunks * 64 f32     = 16384

__device__ __forceinline__ unsigned short f2bf(float f) {
  unsigned u = __builtin_bit_cast(unsigned, f);
  u += 0x7FFFu + ((u >> 16) & 1u);
  return (unsigned short)(u >> 16);
}
__device__ __forceinline__ float sel3(float a, float b, float c, int i) {
  return i == 0 ? a : (i == 1 ? b : c);
}
__device__ __forceinline__ float lse3(float x, float y, float z) {
  float m = fmaxf(fmaxf(x, y), z);
  float p = exp2f((x - m) * L2E) + exp2f((y - m) * L2E) + exp2f((z - m) * L2E);
  return m + log2f(p) * LN2;
}
__device__ __forceinline__ int swz(int row, int slot) {       // byte addr of 16B slot, XOR-swizzled
  return row * 128 + ((slot ^ (row & 7)) << 4);
}

// ---------------- K_A: coalesced weight transposes + lengths + scal zero ---------------------
// blocks 0..95   : wt_type[n][k] = W_type[k][n]  (64x64 tiles, 12 k-tiles x 8 n-tiles)
// blocks 96..107 : wt_all rows 0..63 = W1^T      (64x64 tiles, 12 k-tiles)
// block  108     : wt_all rows 64..79 (Wpos cols + zero pad)
// block  109     : lengths (mask row-sums) + scal[1]=scal[2]=0
__global__ __launch_bounds__(256) void ka_prep(
    const float* __restrict__ W1, const float* __restrict__ Wpos,
    const float* __restrict__ Wtype, const int* __restrict__ amask,
    unsigned short* __restrict__ wt_all, unsigned short* __restrict__ wt_type,
    int* __restrict__ lengths, float* __restrict__ scal) {
  const int bid = blockIdx.x, t = threadIdx.x;
  if (bid < 108) {
    __shared__ float tl[64][65];
    const bool is_type = bid < 96;
    const int kt = is_type ? (bid % 12) : (bid - 96);
    const int k0 = kt * 64;
    const int n0 = is_type ? (bid / 12) * 64 : 0;
    const int ld = is_type ? 500 : 64;
    const int nlim = is_type ? 500 : 64;
    const float* src = is_type ? Wtype : W1;
    unsigned short* dst = is_type ? wt_type : wt_all;
    const int n = t & 63;
    #pragma unroll
    for (int i = 0; i < 16; ++i) {
      int k = i * 4 + (t >> 6);
      tl[k][n] = (n0 + n < nlim) ? src[(size_t)(k0 + k) * ld + n0 + n] : 0.f;
    }
    __syncthreads();
    const int k = t & 63;
    #pragma unroll
    for (int i = 0; i < 16; ++i) {
      int nn = i * 4 + (t >> 6);
      dst[(size_t)(n0 + nn) * 768 + k0 + k] = f2bf(tl[k][nn]);
    }
  } else if (bid == 108) {
    for (int idx = t; idx < 16 * 768; idx += 256) {
      int n = 64 + idx / 768, k = idx % 768;
      float v = (n < 67) ? Wpos[k * 3 + (n - 64)] : 0.f;
      wt_all[(size_t)n * 768 + k] = f2bf(v);
    }
  } else {
    __shared__ int part[256];
    int bb = t >> 2, qq = t & 3;
    const int4* mp = (const int4*)(amask + bb * 512 + qq * 128);
    int s = 0;
    #pragma unroll 8
    for (int i = 0; i < 32; ++i) { int4 v = mp[i]; s += v.x + v.y + v.z + v.w; }
    part[t] = s;
    __syncthreads();
    if (qq == 0) lengths[bb] = part[t] + part[t + 1] + part[t + 2] + part[t + 3];
    if (t == 0) { scal[1] = 0.f; scal[2] = 0.f; }
  }
}

// ---------------- K1: fused [32768x768]@[768x80] bf16 MFMA + epilogue, reg-prefetch ----------
// cols 0..63 = att pre-act -> tanh*W2 reduce -> scores; cols 64..66 = emissions (weighted)
__global__ __launch_bounds__(256) void k1_gemm(
    const float* __restrict__ hidden, const int* __restrict__ plab,
    const float* __restrict__ bpos, const float* __restrict__ b1,
    const float* __restrict__ W2, const float* __restrict__ b2,
    const float* __restrict__ biw, const unsigned short* __restrict__ wt_all,
    float* __restrict__ em_t, float* __restrict__ scores, int* __restrict__ labels_t) {
  __shared__ char lds[8192 + 10240];
  char* As = lds;            // [64 rows][64 k] bf16, swizzled 16B slots
  char* Bs = lds + 8192;     // [80 n  ][64 k] bf16, swizzled
  const int t = threadIdx.x, w = t >> 6, l = t & 63;
  const int row0 = blockIdx.x * 64;

  f32x4 acc[5];
  #pragma unroll
  for (int nt = 0; nt < 5; ++nt) acc[nt] = (f32x4){0.f, 0.f, 0.f, 0.f};

  auto loadAB = [&](int it, float4 av[4], uint4 bv[3]) {
    const int k0 = it * 64;
    #pragma unroll
    for (int u = 0; u < 4; ++u) {
      int f4 = t + 256 * u, r = f4 >> 4, k4 = f4 & 15;
      av[u] = *(const float4*)(hidden + (size_t)(row0 + r) * 768 + k0 + 4 * k4);
    }
    bv[0] = *(const uint4*)(wt_all + (t >> 3) * 768 + k0 + 8 * (t & 7));
    bv[1] = *(const uint4*)(wt_all + ((t + 256) >> 3) * 768 + k0 + 8 * (t & 7));
    bv[2] = (t < 128) ? *(const uint4*)(wt_all + ((t + 512) >> 3) * 768 + k0 + 8 * (t & 7))
                      : (uint4){0, 0, 0, 0};
  };

  float4 avc[4]; uint4 bvc[3];
  loadAB(0, avc, bvc);

  for (int it = 0; it < 12; ++it) {
    __syncthreads();   // previous iteration's LDS reads done
    #pragma unroll
    for (int u = 0; u < 4; ++u) {
      int f4 = t + 256 * u, r = f4 >> 4, k4 = f4 & 15;
      unsigned lo = (unsigned)f2bf(avc[u].x) | ((unsigned)f2bf(avc[u].y) << 16);
      unsigned hi = (unsigned)f2bf(avc[u].z) | ((unsigned)f2bf(avc[u].w) << 16);
      int byte = r * 128 + (((k4 >> 1) ^ (r & 7)) << 4) + (k4 & 1) * 8;
      *(uint2*)(As + byte) = make_uint2(lo, hi);
    }
    { int n = t >> 3, kc = t & 7;         *(uint4*)(Bs + swz(n, kc)) = bvc[0]; }
    { int n = (t + 256) >> 3, kc = t & 7; *(uint4*)(Bs + swz(n, kc)) = bvc[1]; }
    if (t < 128) { int n = (t + 512) >> 3, kc = t & 7; *(uint4*)(Bs + swz(n, kc)) = bvc[2]; }
    __syncthreads();

    float4 avn[4]; uint4 bvn[3];
    if (it < 11) loadAB(it + 1, avn, bvn);     // prefetch next tile during MFMA phase

    #pragma unroll
    for (int ks = 0; ks < 2; ++ks) {
      int arow = 16 * w + (l & 15);
      int slot = 4 * ks + (l >> 4);
      bf16x8 a = *(const bf16x8*)(As + swz(arow, slot));
      #pragma unroll
      for (int nt = 0; nt < 5; ++nt) {
        int brow = 16 * nt + (l & 15);
        bf16x8 b = *(const bf16x8*)(Bs + swz(brow, slot));
        acc[nt] = __builtin_amdgcn_mfma_f32_16x16x32_bf16(a, b, acc[nt], 0, 0, 0);
      }
    }
    if (it < 11) {
      #pragma unroll
      for (int u = 0; u < 4; ++u) avc[u] = avn[u];
      #pragma unroll
      for (int u = 0; u < 3; ++u) bvc[u] = bvn[u];
    }
  }

  // epilogue: D layout col = l&15 (+16*nt), row = 16*w + 4*(l>>4) + reg
  const int q = l >> 4, c16 = l & 15;
  const float bias2 = b2[0];
  #pragma unroll
  for (int r = 0; r < 4; ++r) {
    float s = 0.f;
    #pragma unroll
    for (int nt = 0; nt < 4; ++nt) {
      int c = 16 * nt + c16;
      float x = acc[nt][r] + b1[c];
      float th = 1.f - 2.f / (1.f + exp2f(x * (2.f * L2E)));
      s += th * W2[c];
    }
    #pragma unroll
    for (int off = 1; off < 16; off <<= 1) s += __shfl_xor(s, off, 64);
    if (c16 == 0) {
      int row = row0 + 16 * w + 4 * q + r;
      scores[row] = s + bias2;
    }
  }
  if (c16 < 3) {
    const float bi = biw[0];
    #pragma unroll
    for (int r = 0; r < 4; ++r) {
      int row = row0 + 16 * w + 4 * q + r;
      int bb = row >> 9, ss = row & 511;
      int lab = plab[row];
      float wgt = (lab > 0) ? 1.f + bi : 1.f;
      float ev = (acc[4][r] + bpos[c16]) * wgt;
      em_t[(ss * 3 + c16) * 64 + bb] = ev;
      if (c16 == 0) labels_t[ss * 64 + bb] = lab;
    }
  }
}

// ---------------- K2a: CRF chunk matrices (log-semiring assoc scan, chunk=8) ----------------
__global__ __launch_bounds__(64) void k2a_chunk(
    const float* __restrict__ em_t, const int* __restrict__ labels_t,
    const int* __restrict__ lengths, const float* __restrict__ trans,
    float* __restrict__ matM, float* __restrict__ psc) {
  const int b = threadIdx.x, c = blockIdx.x;
  float T0 = trans[0], T1 = trans[1], T2 = trans[2];
  float T3 = trans[3], T4 = trans[4], T5 = trans[5];
  float T6 = trans[6], T7 = trans[7], T8 = trans[8];
  const int L = lengths[b];
  const int s0 = 8 * c;
  int labp = labels_t[(c ? (s0 - 1) : 0) * 64 + b];

  float E0[8], E1[8], E2[8]; int LB[8];
  #pragma unroll
  for (int i = 0; i < 8; ++i) {
    E0[i] = em_t[((s0 + i) * 3 + 0) * 64 + b];
    E1[i] = em_t[((s0 + i) * 3 + 1) * 64 + b];
    E2[i] = em_t[((s0 + i) * 3 + 2) * 64 + b];
    LB[i] = labels_t[(s0 + i) * 64 + b];
  }

  float M[9];
  #pragma unroll
  for (int i = 0; i < 9; ++i) M[i] = (i == 0 || i == 4 || i == 8) ? 0.f : NEGB;
  float sc = 0.f;

  #pragma unroll
  for (int i = 0; i < 8; ++i) {
    int s = s0 + i;
    bool act = (s >= 1) && (s < L);
    float N[9];
    #pragma unroll
    for (int r = 0; r < 3; ++r) {
      float ma = M[3 * r], mb = M[3 * r + 1], mc = M[3 * r + 2];
      N[3 * r + 0] = lse3(ma + T0, mb + T3, mc + T6) + E0[i];
      N[3 * r + 1] = lse3(ma + T1, mb + T4, mc + T7) + E1[i];
      N[3 * r + 2] = lse3(ma + T2, mb + T5, mc + T8) + E2[i];
    }
    #pragma unroll
    for (int r = 0; r < 9; ++r) M[r] = act ? N[r] : M[r];
    int lab = LB[i];
    float ev = sel3(E0[i], E1[i], E2[i], lab);
    float trv = sel3(sel3(T0, T1, T2, lab),
                     sel3(T3, T4, T5, lab),
                     sel3(T6, T7, T8, lab), labp);
    sc += act ? (ev + trv) : 0.f;
    labp = lab;
  }
  #pragma unroll
  for (int i = 0; i < 9; ++i) matM[(c * 9 + i) * 64 + b] = M[i];
  psc[c * 64 + b] = sc;
}

// ---------------- K_D: fused span-pool + type-GEMM + focal (1 block = 1 batch, 8 spans) ------
__global__ __launch_bounds__(256) void kd_pool_gemm_focal(
    const float* __restrict__ hidden, const float* __restrict__ scores,
    const int* __restrict__ tpos, const int* __restrict__ tlab,
    const unsigned short* __restrict__ wt_type, const float* __restrict__ btype,
    float* __restrict__ scal) {
  __shared__ unsigned short Apool[8][776];    // row stride 1552 B (16B-mult, bank-spread)
  __shared__ float red[4][8][3];              // [wave][row][lmax,sexp,ssum]
  __shared__ float vl[8];
  const int t = threadIdx.x, w = t >> 6, l = t & 63;
  const int b = blockIdx.x;                   // batch; spans b*8 .. b*8+7

  // ---- phase 1: pooled A-tile (8 spans x 768) in bf16
  {
    const int sp = t >> 5;                    // local span 0..7 (32 threads each)
    const int span = b * 8 + sp;
    const int st = tpos[span * 2], en = tpos[span * 2 + 1];
    const int len = (st + en > 0) ? (en - st) : 0;
    float sv[7], aw[7];
    float wm = -1e30f;
    #pragma unroll
    for (int j = 0; j < 7; ++j) {
      sv[j] = (j < len) ? scores[b * 512 + st + j] : -1e30f;
      wm = fmaxf(wm, sv[j]);
    }
    float den = 0.f;
    #pragma unroll
    for (int j = 0; j < 7; ++j) {
      aw[j] = (j < len) ? exp2f((sv[j] - wm) * L2E) : 0.f;
      den += aw[j];
    }
    float inv = (den > 0.f) ? 1.f / den : 0.f;
    #pragma unroll
    for (int j = 0; j < 7; ++j) aw[j] *= inv;

    const int h0 = (t & 31) * 24;             // 24 consecutive h per thread
    float ap[24];
    #pragma unroll
    for (int i = 0; i < 24; ++i) ap[i] = 0.f;
    #pragma unroll
    for (int j = 0; j < 7; ++j) {
      if (j < len) {
        const float4* hp = (const float4*)(hidden + (size_t)(b * 512 + st + j) * 768 + h0);
        #pragma unroll
        for (int i = 0; i < 6; ++i) {
          float4 v = hp[i];
          ap[4 * i + 0] += aw[j] * v.x; ap[4 * i + 1] += aw[j] * v.y;
          ap[4 * i + 2] += aw[j] * v.z; ap[4 * i + 3] += aw[j] * v.w;
        }
      }
    }
    unsigned short* dp = &Apool[sp][h0];
    #pragma unroll
    for (int g = 0; g < 3; ++g) {
      uint4 v;
      v.x = (unsigned)f2bf(ap[8 * g + 0]) | ((unsigned)f2bf(ap[8 * g + 1]) << 16);
      v.y = (unsigned)f2bf(ap[8 * g + 2]) | ((unsigned)f2bf(ap[8 * g + 3]) << 16);
      v.z = (unsigned)f2bf(ap[8 * g + 4]) | ((unsigned)f2bf(ap[8 * g + 5]) << 16);
      v.w = (unsigned)f2bf(ap[8 * g + 6]) | ((unsigned)f2bf(ap[8 * g + 7]) << 16);
      *(uint4*)(dp + 8 * g) = v;
    }
  }
  __syncthreads();

  // ---- phase 2: [8(pad16) x 768] @ wt_type^T -> wave w owns cols [128w, 128w+128)
  f32x4 acc[8];
  #pragma unroll
  for (int nt = 0; nt < 8; ++nt) acc[nt] = (f32x4){0.f, 0.f, 0.f, 0.f};
  const int arow = l & 15;
  const bf16x8 zerov = (bf16x8)(__bf16)0.f;
  for (int ks = 0; ks < 24; ++ks) {
    bf16x8 a = (arow < 8) ? *(const bf16x8*)(&Apool[arow][ks * 32 + 8 * (l >> 4)]) : zerov;
    #pragma unroll
    for (int nt = 0; nt < 8; ++nt) {
      int col = 128 * w + 16 * nt + (l & 15);
      bf16x8 bb = *(const bf16x8*)(wt_type + (size_t)col * 768 + ks * 32 + 8 * (l >> 4));
      acc[nt] = __builtin_amdgcn_mfma_f32_16x16x32_bf16(a, bb, acc[nt], 0, 0, 0);
    }
  }

  // ---- phase 3: focal CE over 500 cols (rows 0..7 live in lanes l>>4 < 2)
  float bt[8]; bool vc[8];
  #pragma unroll
  for (int nt = 0; nt < 8; ++nt) {
    int col = 128 * w + 16 * nt + (l & 15);
    vc[nt] = col < 500;
    bt[nt] = vc[nt] ? btype[col] : 0.f;
  }
  #pragma unroll
  for (int r = 0; r < 4; ++r) {
    // row = 4*(l>>4) + r  (valid when l>>4 < 2)
    float lmax = -1e30f, ssum = 0.f;
    #pragma unroll
    for (int nt = 0; nt < 8; ++nt) {
      float lv = vc[nt] ? (acc[nt][r] + bt[nt]) : -1e30f;
      lmax = fmaxf(lmax, lv);
      ssum += vc[nt] ? lv : 0.f;
    }
    #pragma unroll
    for (int off = 1; off < 16; off <<= 1) lmax = fmaxf(lmax, __shfl_xor(lmax, off, 64));
    float sexp = 0.f;
    #pragma unroll
    for (int nt = 0; nt < 8; ++nt) {
      float lv = vc[nt] ? (acc[nt][r] + bt[nt]) : -1e30f;
      sexp += vc[nt] ? exp2f((lv - lmax) * L2E) : 0.f;
    }
    #pragma unroll
    for (int off = 1; off < 16; off <<= 1) {
      sexp += __shfl_xor(sexp, off, 64);
      ssum += __shfl_xor(ssum, off, 64);
    }
    if ((l & 15) == 0 && (l >> 4) < 2) {
      int row = 4 * (l >> 4) + r;
      red[w][row][0] = lmax; red[w][row][1] = sexp; red[w][row][2] = ssum;
    }
    // gold-label logit extraction
    if ((l >> 4) < 2) {
      int row = 4 * (l >> 4) + r;
      int lbl = tlab[b * 8 + row];
      if ((lbl >> 7) == w && (lbl & 15) == (l & 15)) {
        #pragma unroll
        for (int nt = 0; nt < 8; ++nt)
          if (((lbl >> 4) & 7) == nt) vl[row] = acc[nt][r] + btype[lbl];
      }
    }
  }
  __syncthreads();

  float fv = 0.f, vv = 0.f;
  if (t < 8) {
    const int row = t;
    float gm = fmaxf(fmaxf(red[0][row][0], red[1][row][0]),
                     fmaxf(red[2][row][0], red[3][row][0]));
    float sexp = 0.f, ssum = 0.f;
    #pragma unroll
    for (int i = 0; i < 4; ++i) {
      sexp += red[i][row][1] * exp2f((red[i][row][0] - gm) * L2E);
      ssum += red[i][row][2];
    }
    float logZ = gm + log2f(sexp) * LN2;
    float lp = vl[row] - logZ;
    float ce = -(0.9f * lp + 2e-4f * (ssum - 500.f * logZ));
    float pt = 0.9f * exp2f(lp * L2E) + 2e-4f;
    float focal = ce * (1.f - pt) * (1.f - pt);
    int span = b * 8 + row;
    bool valid = (tpos[span * 2] + tpos[span * 2 + 1]) > 0;
    fv = valid ? focal : 0.f;
    vv = valid ? 1.f : 0.f;
  }
  #pragma unroll
  for (int off = 1; off < 8; off <<= 1) {
    fv += __shfl_xor(fv, off, 64);
    vv += __shfl_xor(vv, off, 64);
  }
  if (t == 0) {
    atomicAdd(&scal[1], fv);
    atomicAdd(&scal[2], vv);
  }
}

// ---------------- K_E: CRF chunk-scan (4-chunk banked prefetch) + combine --------------------
__global__ __launch_bounds__(64) void k_final(
    const float* __restrict__ em_t, const int* __restrict__ labels_t,
    const int* __restrict__ lengths, const float* __restrict__ strans,
    const float* __restrict__ etrans, const float* __restrict__ matM,
    const float* __restrict__ psc, const float* __restrict__ scal,
    float* __restrict__ out) {
  const int b = threadIdx.x;
  const int L = lengths[b];
  const float st0 = strans[0], st1 = strans[1], st2 = strans[2];
  const float et0 = etrans[0], et1 = etrans[1], et2 = etrans[2];
  float e00 = em_t[0 * 64 + b], e01 = em_t[1 * 64 + b], e02 = em_t[2 * 64 + b];
  int lab0 = labels_t[b];
  float a0 = st0 + e00, a1 = st1 + e01, a2 = st2 + e02;
  float score = sel3(st0, st1, st2, lab0) + sel3(e00, e01, e02, lab0);

  float cur[4][10];
  #pragma unroll
  for (int j = 0; j < 4; ++j) {
    #pragma unroll
    for (int i = 0; i < 9; ++i) cur[j][i] = matM[(j * 9 + i) * 64 + b];
    cur[j][9] = psc[j * 64 + b];
  }

  for (int r = 0; r < 16; ++r) {
    float nxt[4][10];
    if (r < 15) {
      #pragma unroll
      for (int j = 0; j < 4; ++j) {
        int c = (r + 1) * 4 + j;
        #pragma unroll
        for (int i = 0; i < 9; ++i) nxt[j][i] = matM[(c * 9 + i) * 64 + b];
        nxt[j][9] = psc[c * 64 + b];
      }
    }
    #pragma unroll
    for (int j = 0; j < 4; ++j) {
      float n0 = lse3(a0 + cur[j][0], a1 + cur[j][3], a2 + cur[j][6]);
      float n1 = lse3(a0 + cur[j][1], a1 + cur[j][4], a2 + cur[j][7]);
      float n2 = lse3(a0 + cur[j][2], a1 + cur[j][5], a2 + cur[j][8]);
      a0 = n0; a1 = n1; a2 = n2;
      score += cur[j][9];
    }
    if (r < 15) {
      #pragma unroll
      for (int j = 0; j < 4; ++j)
        #pragma unroll
        for (int i = 0; i < 10; ++i) cur[j][i] = nxt[j][i];
    }
  }

  int last = labels_t[(L - 1) * 64 + b];
  score += sel3(et0, et1, et2, last);
  float logZ = lse3(a0 + et0, a1 + et1, a2 + et2);
  float nll = logZ - score;
  #pragma unroll
  for (int off = 1; off < 64; off <<= 1) nll += __shfl_xor(nll, off, 64);
  if (b == 0) {
    float pos = nll / 64.f;
    float type = scal[1] / fmaxf(scal[2], 1.f) * 10.f;
    out[0] = 0.6f * pos + 0.4f * type;
    out[1] = pos;
    out[2] = type;
  }
}

extern "C" void kernel_launch(void* const* d_in, const int* in_sizes, int n_in,
                              void* d_out, int out_size, void* d_ws, size_t ws_size,
                              hipStream_t stream) {
  const float* hidden = (const float*)d_in[0];
  const int*   amask  = (const int*)d_in[1];
  const int*   plab   = (const int*)d_in[2];
  const int*   tlab   = (const int*)d_in[3];
  const int*   tpos   = (const int*)d_in[4];
  const float* biw    = (const float*)d_in[5];
  const float* Wpos   = (const float*)d_in[6];
  const float* bpos   = (const float*)d_in[7];
  const float* strans = (const float*)d_in[8];
  const float* etrans = (const float*)d_in[9];
  const float* trans  = (const float*)d_in[10];
  const float* W1     = (const float*)d_in[11];
  const float* b1     = (const float*)d_in[12];
  const float* W2     = (const float*)d_in[13];
  const float* b2     = (const float*)d_in[14];
  const float* Wtype  = (const float*)d_in[15];
  const float* btype  = (const float*)d_in[16];
  float* out = (float*)d_out;
  char* ws = (char*)d_ws;

  unsigned short* wt_all  = (unsigned short*)(ws + WT_ALL_OFF);
  unsigned short* wt_type = (unsigned short*)(ws + WT_TYPE_OFF);
  float* em_t    = (float*)(ws + EM_T_OFF);
  float* scores  = (float*)(ws + SCORES_OFF);
  int*   labelsT = (int*)(ws + LABELS_T_OFF);
  int*   lengths = (int*)(ws + LEN_OFF);
  float* scal    = (float*)(ws + SCAL_OFF);
  float* matM    = (float*)(ws + MATM_OFF);
  float* psc     = (float*)(ws + PSC_OFF);

  ka_prep<<<110, 256, 0, stream>>>(W1, Wpos, Wtype, amask, wt_all, wt_type, lengths, scal);
  k1_gemm<<<512, 256, 0, stream>>>(hidden, plab, bpos, b1, W2, b2, biw, wt_all,
                                   em_t, scores, labelsT);
  k2a_chunk<<<64, 64, 0, stream>>>(em_t, labelsT, lengths, trans, matM, psc);
  kd_pool_gemm_focal<<<64, 256, 0, stream>>>(hidden, scores, tpos, tlab, wt_type, btype, scal);
  k_final<<<1, 64, 0, stream>>>(em_t, labelsT, lengths, strans, etrans, matM, psc, scal, out);
}